// Round 8
// baseline (185.641 us; speedup 1.0000x reference)
//
#include <hip/hip_runtime.h>
#include <hip/hip_fp16.h>
#include <stdint.h>

#define BATCH 4096
#define N_IN  512
#define H1    1536
#define H2    1536
#define N_OUT 512
#define FAN   32
#define E0 (H1 * FAN)
#define E1 (H2 * FAN)
#define E2 (N_OUT * FAN)
#define ETOT (E0 + E1 + E2)
#define K1 N_IN               // 512
#define K2 (N_IN + H1)        // 2048
#define K3 (N_IN + H1 + H2)   // 3584

// nvT: activations batch-major [4096][NVSTRIDE] fp16. cols 0..511 = x,
// 512..2047 = h1, 2048..3583 = h2. K-contiguous => both GEMM operands K-major.
// Stride 3648 halfs = 57 x 128B lines (odd line count: no L1/L2 set aliasing
// on the 128-row staging reads).
#define NVSTRIDE 3648
#define NVBYTES  ((size_t)BATCH * NVSTRIDE * 2)         // 29,884,416
#define W0BYTES  ((size_t)H1 * K1 * 2)                  //  1,572,864
#define W1BYTES  ((size_t)H2 * K2 * 2)                  //  6,291,456
#define W2BYTES  ((size_t)N_OUT * K3 * 2)               //  3,670,016

typedef _Float16 f16x8 __attribute__((ext_vector_type(8)));
typedef float    f32x4 __attribute__((ext_vector_type(4)));

// ---------- x [B][512] fp32 -> nvT cols 0..511 fp16 (no transpose needed!) ----------
__global__ __launch_bounds__(256) void k_xcvt(const float* __restrict__ x,
                                              __half* __restrict__ nvT) {
    const int t  = blockIdx.x * 256 + threadIdx.x;   // 0 .. 4096*64-1
    const int n  = t >> 6;
    const int c8 = t & 63;
    const float4 f0 = *(const float4*)(x + (size_t)n * N_IN + c8 * 8);
    const float4 f1 = *(const float4*)(x + (size_t)n * N_IN + c8 * 8 + 4);
    const __half2 a = __floats2half2_rn(f0.x, f0.y);
    const __half2 b = __floats2half2_rn(f0.z, f0.w);
    const __half2 c = __floats2half2_rn(f1.x, f1.y);
    const __half2 d = __floats2half2_rn(f1.z, f1.w);
    uint4 u;
    u.x = *(const uint32_t*)&a; u.y = *(const uint32_t*)&b;
    u.z = *(const uint32_t*)&c; u.w = *(const uint32_t*)&d;
    *(uint4*)(nvT + (size_t)n * NVSTRIDE + c8 * 8) = u;
}

// ---------- fp16 scatter-add (CAS on containing dword; duplicates accumulate) ----------
__device__ __forceinline__ void atomic_add_half(__half* addr, float val) {
    uint32_t* base = (uint32_t*)((size_t)addr & ~(size_t)3);
    const bool hi  = ((size_t)addr & 2) != 0;
    uint32_t old = *base, assumed;
    do {
        assumed = old;
        __half2 h2 = *(__half2*)&assumed;
        float f = (hi ? __high2float(h2) : __low2float(h2)) + val;
        __half2 nh = hi ? __halves2half2(__low2half(h2), __float2half_rn(f))
                        : __halves2half2(__float2half_rn(f), __high2half(h2));
        old = atomicCAS(base, assumed, *(uint32_t*)&nh);
    } while (old != assumed);
}

__global__ __launch_bounds__(256) void k_wfill(const int* __restrict__ src,
                                               const int* __restrict__ dst,
                                               const float* __restrict__ w,
                                               __half* __restrict__ Wd, const int K) {
    const int e = blockIdx.x * 256 + threadIdx.x;
    atomic_add_half(Wd + (size_t)dst[e] * K + src[e], w[e]);
}

__global__ __launch_bounds__(256) void k_wfill_all(
        const int* __restrict__ s0, const int* __restrict__ d0, const float* __restrict__ w0,
        const int* __restrict__ s1, const int* __restrict__ d1, const float* __restrict__ w1,
        const int* __restrict__ s2, const int* __restrict__ d2, const float* __restrict__ w2,
        __half* __restrict__ W0d, __half* __restrict__ W1d, __half* __restrict__ W2d) {
    const int e = blockIdx.x * 256 + threadIdx.x;
    if (e < E0)            atomic_add_half(W0d + (size_t)d0[e] * K1 + s0[e], w0[e]);
    else if (e < E0 + E1) { const int i = e - E0;      atomic_add_half(W1d + (size_t)d1[i] * K2 + s1[i], w1[i]); }
    else                  { const int i = e - E0 - E1; atomic_add_half(W2d + (size_t)d2[i] * K3 + s2[i], w2[i]); }
}

// ---------- MFMA GEMM: C[m][n] = relu(sum_k A[m][k] * Bt[n][k]) ----------
// m97-proven structure: 128-wide N tile, BK=64, 256 thr = 4 waves (2x2), each
// wave FMx4 fragments of 16x16, global_load_lds width-16 staging with
// pre-swizzled SOURCE chunks (LDS dest linear, read chunk XOR (row&7) -- the
// same involution both sides, rule #21). Fragments: lane l holds 8 contiguous
// k-halfs at row l&15, chunk kk*4+(l>>4) (verified layout, m92/m97 refcheckd).
// Output: fp16 into nvT col block (8B/lane) or fp32 into d_out (16B/lane).
template<int BM, bool F32OUT>
__global__ __launch_bounds__(256, BM == 128 ? 3 : 4)
void k_gemm(const __half* __restrict__ A,    // [M][K] dense W, row stride K
            const __half* __restrict__ Bt,   // nvT, row stride NVSTRIDE
            __half* __restrict__ Ch,         // nvT + col0 (if !F32OUT)
            float* __restrict__ Cf,          // d_out (if F32OUT)
            const int K) {
    constexpr int FM = BM / 32;              // fragments per wave in M
    constexpr int WR = BM / 2;               // rows per wave-row
    __shared__ __half lA[BM * 64];
    __shared__ __half lB[128 * 64];
    const int tid  = threadIdx.x;
    const int lane = tid & 63;
    const int wv   = tid >> 6;
    const int wr   = wv >> 1, wc = wv & 1;
    const int m0   = blockIdx.y * BM;
    const int n0   = blockIdx.x * 128;
    const int lrow = lane >> 3;              // staging: row-in-8-group
    const int lchk = lane & 7;               // staging: chunk 0..7

    f32x4 acc[FM][4] = {};

    for (int kt = 0; kt < K; kt += 64) {
        // ---- stage A tile [BM][64] ----
#pragma unroll
        for (int it = 0; it < BM / 32; ++it) {
            const int row = it * 32 + wv * 8 + lrow;
            const int sc  = lchk ^ (row & 7);
            __builtin_amdgcn_global_load_lds(
                (const __attribute__((address_space(1))) void*)(const void*)
                    (A + (size_t)(m0 + row) * K + kt + sc * 8),
                (__attribute__((address_space(3))) void*)(void*)
                    (lA + (it * 32 + wv * 8) * 64),
                16, 0, 0);
        }
        // ---- stage B tile [128][64] ----
#pragma unroll
        for (int it = 0; it < 4; ++it) {
            const int row = it * 32 + wv * 8 + lrow;
            const int sc  = lchk ^ (row & 7);
            __builtin_amdgcn_global_load_lds(
                (const __attribute__((address_space(1))) void*)(const void*)
                    (Bt + (size_t)(n0 + row) * NVSTRIDE + kt + sc * 8),
                (__attribute__((address_space(3))) void*)(void*)
                    (lB + (it * 32 + wv * 8) * 64),
                16, 0, 0);
        }
        __syncthreads();   // compiler emits full vmcnt/lgkm drain before s_barrier

#pragma unroll
        for (int kk = 0; kk < 2; ++kk) {
            f16x8 af[FM], bf[4];
#pragma unroll
            for (int fm = 0; fm < FM; ++fm) {
                const int row = wr * WR + fm * 16 + (lane & 15);
                const int ch  = (kk * 4 + (lane >> 4)) ^ (row & 7);
                af[fm] = *(const f16x8*)(lA + row * 64 + ch * 8);
            }
#pragma unroll
            for (int fn = 0; fn < 4; ++fn) {
                const int row = wc * 64 + fn * 16 + (lane & 15);
                const int ch  = (kk * 4 + (lane >> 4)) ^ (row & 7);
                bf[fn] = *(const f16x8*)(lB + row * 64 + ch * 8);
            }
#pragma unroll
            for (int fm = 0; fm < FM; ++fm)
#pragma unroll
                for (int fn = 0; fn < 4; ++fn)
                    acc[fm][fn] = __builtin_amdgcn_mfma_f32_16x16x32_f16(
                        af[fm], bf[fn], acc[fm][fn], 0, 0, 0);
        }
        __syncthreads();
    }

    // ---- epilogue: relu + store. D mapping: col=lane&15, row=(lane>>4)*4+reg ----
    const int cm = (lane >> 4) << 2;
    const int cn = lane & 15;
#pragma unroll
    for (int fm = 0; fm < FM; ++fm) {
#pragma unroll
        for (int fn = 0; fn < 4; ++fn) {
            const f32x4 v = acc[fm][fn];
            const float r0 = fmaxf(v[0], 0.f), r1 = fmaxf(v[1], 0.f);
            const float r2 = fmaxf(v[2], 0.f), r3 = fmaxf(v[3], 0.f);
            const int mm = m0 + wr * WR + fm * 16 + cm;
            const int nn = n0 + wc * 64 + fn * 16 + cn;
            if constexpr (F32OUT) {
                float4 o; o.x = r0; o.y = r1; o.z = r2; o.w = r3;
                *(float4*)(Cf + (size_t)nn * N_OUT + mm) = o;
            } else {
                const __half2 p0 = __floats2half2_rn(r0, r1);
                const __half2 p1 = __floats2half2_rn(r2, r3);
                uint2 u; u.x = *(const uint32_t*)&p0; u.y = *(const uint32_t*)&p1;
                *(uint2*)(Ch + (size_t)nn * NVSTRIDE + mm) = u;
            }
        }
    }
}

extern "C" void kernel_launch(void* const* d_in, const int* in_sizes, int n_in,
                              void* d_out, int out_size, void* d_ws, size_t ws_size,
                              hipStream_t stream) {
    const float* x  = (const float*)d_in[0];
    const int* s0   = (const int*)d_in[1];
    const int* dd0  = (const int*)d_in[2];
    const float* w0 = (const float*)d_in[3];
    const int* s1   = (const int*)d_in[4];
    const int* dd1  = (const int*)d_in[5];
    const float* w1 = (const float*)d_in[6];
    const int* s2   = (const int*)d_in[7];
    const int* dd2  = (const int*)d_in[8];
    const float* w2 = (const float*)d_in[9];

    char*   ws  = (char*)d_ws;
    __half* nvT = (__half*)ws;
    float*  out = (float*)d_out;

    // x -> nvT cols 0..511 (fp32->fp16, coalesced, no transpose)
    k_xcvt<<<BATCH * 64 / 256, 256, 0, stream>>>(x, nvT);

    if (ws_size >= NVBYTES + W0BYTES + W1BYTES + W2BYTES) {
        // separate W buffers: one memset + one fused fill (fewest dispatches)
        __half* W0p = (__half*)(ws + NVBYTES);
        __half* W1p = (__half*)(ws + NVBYTES + W0BYTES);
        __half* W2p = (__half*)(ws + NVBYTES + W0BYTES + W1BYTES);
        hipMemsetAsync(W0p, 0, W0BYTES + W1BYTES + W2BYTES, stream);
        k_wfill_all<<<ETOT / 256, 256, 0, stream>>>(s0, dd0, w0, s1, dd1, w1,
                                                    s2, dd2, w2, W0p, W1p, W2p);
        k_gemm<128, false><<<dim3(BATCH / 128, H1 / 128), 256, 0, stream>>>(
            W0p, nvT, nvT + N_IN, nullptr, K1);
        k_gemm<128, false><<<dim3(BATCH / 128, H2 / 128), 256, 0, stream>>>(
            W1p, nvT, nvT + K2, nullptr, K2);
        k_gemm<64, true><<<dim3(BATCH / 128, N_OUT / 64), 256, 0, stream>>>(
            W2p, nvT, nullptr, out, K3);
    } else {
        // shared W region (36.2 MB total, fits the proven workspace): serialize
        __half* Wp = (__half*)(ws + NVBYTES);
        hipMemsetAsync(Wp, 0, W0BYTES, stream);
        k_wfill<<<E0 / 256, 256, 0, stream>>>(s0, dd0, w0, Wp, K1);
        k_gemm<128, false><<<dim3(BATCH / 128, H1 / 128), 256, 0, stream>>>(
            Wp, nvT, nvT + N_IN, nullptr, K1);
        hipMemsetAsync(Wp, 0, W1BYTES, stream);
        k_wfill<<<E1 / 256, 256, 0, stream>>>(s1, dd1, w1, Wp, K2);
        k_gemm<128, false><<<dim3(BATCH / 128, H2 / 128), 256, 0, stream>>>(
            Wp, nvT, nvT + K2, nullptr, K2);
        hipMemsetAsync(Wp, 0, W2BYTES, stream);
        k_wfill<<<E2 / 256, 256, 0, stream>>>(s2, dd2, w2, Wp, K3);
        k_gemm<64, true><<<dim3(BATCH / 128, N_OUT / 64), 256, 0, stream>>>(
            Wp, nvT, nullptr, out, K3);
    }
}

// Round 9
// 171.988 us; speedup vs baseline: 1.0794x; 1.0794x over previous
//
#include <hip/hip_runtime.h>
#include <hip/hip_fp16.h>
#include <stdint.h>

#define BATCH 4096
#define N_IN  512
#define H1    1536
#define H2    1536
#define N_OUT 512
#define FAN   32
#define E0 (H1 * FAN)
#define E1 (H2 * FAN)
#define E2 (N_OUT * FAN)
#define ETOT (E0 + E1 + E2)
#define K1 N_IN               // 512
#define K2 (N_IN + H1)        // 2048
#define K3 (N_IN + H1 + H2)   // 3584

// nvT: activations batch-major [4096][NVSTRIDE] fp16. cols 0..511 = x,
// 512..2047 = h1, 2048..3583 = h2. K-contiguous => both GEMM operands K-major.
#define NVSTRIDE 3648
#define NVBYTES  ((size_t)BATCH * NVSTRIDE * 2)         // 29,884,416
#define W0BYTES  ((size_t)H1 * K1 * 2)                  //  1,572,864
#define W1BYTES  ((size_t)H2 * K2 * 2)                  //  6,291,456
#define W2BYTES  ((size_t)N_OUT * K3 * 2)               //  3,670,016

typedef _Float16 f16x8 __attribute__((ext_vector_type(8)));
typedef float    f32x4 __attribute__((ext_vector_type(4)));

// ---------- x [B][512] fp32 -> nvT cols 0..511 fp16 ----------
__global__ __launch_bounds__(256) void k_xcvt(const float* __restrict__ x,
                                              __half* __restrict__ nvT) {
    const int t  = blockIdx.x * 256 + threadIdx.x;   // 0 .. 4096*64-1
    const int n  = t >> 6;
    const int c8 = t & 63;
    const float4 f0 = *(const float4*)(x + (size_t)n * N_IN + c8 * 8);
    const float4 f1 = *(const float4*)(x + (size_t)n * N_IN + c8 * 8 + 4);
    const __half2 a = __floats2half2_rn(f0.x, f0.y);
    const __half2 b = __floats2half2_rn(f0.z, f0.w);
    const __half2 c = __floats2half2_rn(f1.x, f1.y);
    const __half2 d = __floats2half2_rn(f1.z, f1.w);
    uint4 u;
    u.x = *(const uint32_t*)&a; u.y = *(const uint32_t*)&b;
    u.z = *(const uint32_t*)&c; u.w = *(const uint32_t*)&d;
    *(uint4*)(nvT + (size_t)n * NVSTRIDE + c8 * 8) = u;
}

// ---------- fp16 scatter-add (CAS on containing dword; duplicates accumulate) ----------
__device__ __forceinline__ void atomic_add_half(__half* addr, float val) {
    uint32_t* base = (uint32_t*)((size_t)addr & ~(size_t)3);
    const bool hi  = ((size_t)addr & 2) != 0;
    uint32_t old = *base, assumed;
    do {
        assumed = old;
        __half2 h2 = *(__half2*)&assumed;
        float f = (hi ? __high2float(h2) : __low2float(h2)) + val;
        __half2 nh = hi ? __halves2half2(__low2half(h2), __float2half_rn(f))
                        : __halves2half2(__float2half_rn(f), __high2half(h2));
        old = atomicCAS(base, assumed, *(uint32_t*)&nh);
    } while (old != assumed);
}

__global__ __launch_bounds__(256) void k_wfill(const int* __restrict__ src,
                                               const int* __restrict__ dst,
                                               const float* __restrict__ w,
                                               __half* __restrict__ Wd, const int K) {
    const int e = blockIdx.x * 256 + threadIdx.x;
    atomic_add_half(Wd + (size_t)dst[e] * K + src[e], w[e]);
}

__global__ __launch_bounds__(256) void k_wfill_all(
        const int* __restrict__ s0, const int* __restrict__ d0, const float* __restrict__ w0,
        const int* __restrict__ s1, const int* __restrict__ d1, const float* __restrict__ w1,
        const int* __restrict__ s2, const int* __restrict__ d2, const float* __restrict__ w2,
        __half* __restrict__ W0d, __half* __restrict__ W1d, __half* __restrict__ W2d) {
    const int e = blockIdx.x * 256 + threadIdx.x;
    if (e < E0)            atomic_add_half(W0d + (size_t)d0[e] * K1 + s0[e], w0[e]);
    else if (e < E0 + E1) { const int i = e - E0;      atomic_add_half(W1d + (size_t)d1[i] * K2 + s1[i], w1[i]); }
    else                  { const int i = e - E0 - E1; atomic_add_half(W2d + (size_t)d2[i] * K3 + s2[i], w2[i]); }
}

// ---------- MFMA GEMM, 2-phase double-buffered (T3-minimum schedule) ----------
// C[m][n] = relu(sum_k A[m][k] * Bt[n][k]).  BN = 128 fixed, BK = 64.
// Per K-step: issue STAGE(buf^1, t+1) FIRST (async global_load_lds into the other
// buffer), then ds_read+MFMA from buf, then ONE __syncthreads() (its implicit
// vmcnt(0)+lgkmcnt(0) drain is exactly the wait needed: t+1's loads landed while
// MFMA ran). Halves barriers/step vs R8 and keeps the staging engine busy.
// R8 occupancy autopsy: GEMM tiles must cover the machine — BM=96 gives
// 16x32 = 512 tiles = exactly 2 blocks/CU (LDS 56KB dbuf -> 2/CU), no tail.
// Fragment/swizzle addressing identical to R8 (refcheck-proven).
template<int BM, bool F32OUT>
__global__ __launch_bounds__(256, 2)
void k_gemm(const __half* __restrict__ A,    // [M][K] dense W, row stride K
            const __half* __restrict__ Bt,   // nvT, row stride NVSTRIDE
            __half* __restrict__ Ch,         // nvT + col0 (if !F32OUT)
            float* __restrict__ Cf,          // d_out (if F32OUT)
            const int K) {
    constexpr int FM = BM / 32;              // 16-row fragments per wave in M
    constexpr int WR = BM / 2;               // rows per wave-row
    __shared__ __half lA[2][BM * 64];
    __shared__ __half lB[2][128 * 64];
    const int tid  = threadIdx.x;
    const int lane = tid & 63;
    const int wv   = tid >> 6;
    const int wr   = wv >> 1, wc = wv & 1;
    const int m0   = blockIdx.y * BM;
    const int n0   = blockIdx.x * 128;
    const int lrow = lane >> 3;              // staging: row-in-8-group
    const int lchk = lane & 7;               // staging: chunk 0..7

    f32x4 acc[FM][4] = {};

#define STAGE(BUF, KT) {                                                         \
    _Pragma("unroll")                                                            \
    for (int it = 0; it < BM / 32; ++it) {                                       \
        const int row = it * 32 + wv * 8 + lrow;                                 \
        const int sc  = lchk ^ (row & 7);                                        \
        __builtin_amdgcn_global_load_lds(                                        \
            (const __attribute__((address_space(1))) void*)(const void*)         \
                (A + (size_t)(m0 + row) * K + (KT) + sc * 8),                    \
            (__attribute__((address_space(3))) void*)(void*)                     \
                (lA[BUF] + (it * 32 + wv * 8) * 64),                             \
            16, 0, 0);                                                           \
    }                                                                            \
    _Pragma("unroll")                                                            \
    for (int it = 0; it < 4; ++it) {                                             \
        const int row = it * 32 + wv * 8 + lrow;                                 \
        const int sc  = lchk ^ (row & 7);                                        \
        __builtin_amdgcn_global_load_lds(                                        \
            (const __attribute__((address_space(1))) void*)(const void*)         \
                (Bt + (size_t)(n0 + row) * NVSTRIDE + (KT) + sc * 8),            \
            (__attribute__((address_space(3))) void*)(void*)                     \
                (lB[BUF] + (it * 32 + wv * 8) * 64),                             \
            16, 0, 0);                                                           \
    }                                                                            \
}

    const int NT = K >> 6;
    // prologue: fill buffer 0; __syncthreads drains vmcnt(0) before s_barrier
    STAGE(0, 0)
    __syncthreads();

    int cur = 0;
    for (int t = 0; t < NT; ++t) {
        if (t + 1 < NT) STAGE(cur ^ 1, (t + 1) << 6)
#pragma unroll
        for (int kk = 0; kk < 2; ++kk) {
            f16x8 af[FM], bf[4];
#pragma unroll
            for (int fm = 0; fm < FM; ++fm) {
                const int row = wr * WR + fm * 16 + (lane & 15);
                const int ch  = (kk * 4 + (lane >> 4)) ^ (row & 7);
                af[fm] = *(const f16x8*)(lA[cur] + row * 64 + ch * 8);
            }
#pragma unroll
            for (int fn = 0; fn < 4; ++fn) {
                const int row = wc * 64 + fn * 16 + (lane & 15);
                const int ch  = (kk * 4 + (lane >> 4)) ^ (row & 7);
                bf[fn] = *(const f16x8*)(lB[cur] + row * 64 + ch * 8);
            }
#pragma unroll
            for (int fm = 0; fm < FM; ++fm)
#pragma unroll
                for (int fn = 0; fn < 4; ++fn)
                    acc[fm][fn] = __builtin_amdgcn_mfma_f32_16x16x32_f16(
                        af[fm], bf[fn], acc[fm][fn], 0, 0, 0);
        }
        __syncthreads();   // waits t+1 loads (vmcnt) + all waves done reading cur
        cur ^= 1;
    }
#undef STAGE

    // ---- epilogue: relu + store. D mapping: col=lane&15, row=(lane>>4)*4+reg ----
    const int cm = (lane >> 4) << 2;
    const int cn = lane & 15;
#pragma unroll
    for (int fm = 0; fm < FM; ++fm) {
#pragma unroll
        for (int fn = 0; fn < 4; ++fn) {
            const f32x4 v = acc[fm][fn];
            const float r0 = fmaxf(v[0], 0.f), r1 = fmaxf(v[1], 0.f);
            const float r2 = fmaxf(v[2], 0.f), r3 = fmaxf(v[3], 0.f);
            const int mm = m0 + wr * WR + fm * 16 + cm;
            const int nn = n0 + wc * 64 + fn * 16 + cn;
            if constexpr (F32OUT) {
                float4 o; o.x = r0; o.y = r1; o.z = r2; o.w = r3;
                *(float4*)(Cf + (size_t)nn * N_OUT + mm) = o;
            } else {
                const __half2 p0 = __floats2half2_rn(r0, r1);
                const __half2 p1 = __floats2half2_rn(r2, r3);
                uint2 u; u.x = *(const uint32_t*)&p0; u.y = *(const uint32_t*)&p1;
                *(uint2*)(Ch + (size_t)nn * NVSTRIDE + mm) = u;
            }
        }
    }
}

extern "C" void kernel_launch(void* const* d_in, const int* in_sizes, int n_in,
                              void* d_out, int out_size, void* d_ws, size_t ws_size,
                              hipStream_t stream) {
    const float* x  = (const float*)d_in[0];
    const int* s0   = (const int*)d_in[1];
    const int* dd0  = (const int*)d_in[2];
    const float* w0 = (const float*)d_in[3];
    const int* s1   = (const int*)d_in[4];
    const int* dd1  = (const int*)d_in[5];
    const float* w1 = (const float*)d_in[6];
    const int* s2   = (const int*)d_in[7];
    const int* dd2  = (const int*)d_in[8];
    const float* w2 = (const float*)d_in[9];

    char*   ws  = (char*)d_ws;
    __half* nvT = (__half*)ws;
    float*  out = (float*)d_out;

    // x -> nvT cols 0..511 (fp32->fp16, coalesced, no transpose)
    k_xcvt<<<BATCH * 64 / 256, 256, 0, stream>>>(x, nvT);

    if (ws_size >= NVBYTES + W0BYTES + W1BYTES + W2BYTES) {
        // separate W buffers: one memset + one fused fill (fewest dispatches)
        __half* W0p = (__half*)(ws + NVBYTES);
        __half* W1p = (__half*)(ws + NVBYTES + W0BYTES);
        __half* W2p = (__half*)(ws + NVBYTES + W0BYTES + W1BYTES);
        hipMemsetAsync(W0p, 0, W0BYTES + W1BYTES + W2BYTES, stream);
        k_wfill_all<<<ETOT / 256, 256, 0, stream>>>(s0, dd0, w0, s1, dd1, w1,
                                                    s2, dd2, w2, W0p, W1p, W2p);
        k_gemm<96, false><<<dim3(BATCH / 128, H1 / 96), 256, 0, stream>>>(
            W0p, nvT, nvT + N_IN, nullptr, K1);
        k_gemm<96, false><<<dim3(BATCH / 128, H2 / 96), 256, 0, stream>>>(
            W1p, nvT, nvT + K2, nullptr, K2);
        k_gemm<64, true><<<dim3(BATCH / 128, N_OUT / 64), 256, 0, stream>>>(
            W2p, nvT, nullptr, out, K3);
    } else {
        // shared W region (36.2 MB total, fits the proven workspace): serialize
        __half* Wp = (__half*)(ws + NVBYTES);
        hipMemsetAsync(Wp, 0, W0BYTES, stream);
        k_wfill<<<E0 / 256, 256, 0, stream>>>(s0, dd0, w0, Wp, K1);
        k_gemm<96, false><<<dim3(BATCH / 128, H1 / 96), 256, 0, stream>>>(
            Wp, nvT, nvT + N_IN, nullptr, K1);
        hipMemsetAsync(Wp, 0, W1BYTES, stream);
        k_wfill<<<E1 / 256, 256, 0, stream>>>(s1, dd1, w1, Wp, K2);
        k_gemm<96, false><<<dim3(BATCH / 128, H2 / 96), 256, 0, stream>>>(
            Wp, nvT, nvT + K2, nullptr, K2);
        hipMemsetAsync(Wp, 0, W2BYTES, stream);
        k_wfill<<<E2 / 256, 256, 0, stream>>>(s2, dd2, w2, Wp, K3);
        k_gemm<64, true><<<dim3(BATCH / 128, N_OUT / 64), 256, 0, stream>>>(
            Wp, nvT, nullptr, out, K3);
    }
}

// Round 10
// 161.354 us; speedup vs baseline: 1.1505x; 1.0659x over previous
//
#include <hip/hip_runtime.h>
#include <hip/hip_fp16.h>
#include <stdint.h>

#define BATCH 4096
#define N_IN  512
#define H1    1536
#define H2    1536
#define N_OUT 512
#define FAN   32
#define E0 (H1 * FAN)
#define E1 (H2 * FAN)
#define E2 (N_OUT * FAN)
#define K1 N_IN               // 512
#define K2 (N_IN + H1)        // 2048
#define K3 (N_IN + H1 + H2)   // 3584

// nvT: activations batch-major [4096][3584] fp16. cols 0..511 = x,
// 512..2047 = h1, 2048..3583 = h2. K-contiguous: both GEMM operands K-major.
#define NVSTRIDE 3584
#define NVBYTES  ((size_t)BATCH * NVSTRIDE * 2)         // 29,360,128
#define W0BYTES  ((size_t)H1 * K1 * 2)                  //  1,572,864
#define W1BYTES  ((size_t)H2 * K2 * 2)                  //  6,291,456
#define W2BYTES  ((size_t)N_OUT * K3 * 2)               //  3,670,016
// W region: [W0 | W1] = 7,864,320 bytes; W2 (3.67 MB) overlays it after GEMM2.
// Total ws = 29,360,128 + 7,864,320 = 37,224,448  (< 37,238,784 proven in R0)

typedef _Float16 f16x8 __attribute__((ext_vector_type(8)));
typedef float    f32x4 __attribute__((ext_vector_type(4)));

#define GLL(SRC, DST)                                                        \
    __builtin_amdgcn_global_load_lds(                                        \
        (const __attribute__((address_space(1))) void*)(const void*)(SRC),   \
        (__attribute__((address_space(3))) void*)(void*)(DST), 16, 0, 0)

// ---------- x [B][512] fp32 -> nvT cols 0..511 fp16 ----------
__global__ __launch_bounds__(256) void k_xcvt(const float* __restrict__ x,
                                              __half* __restrict__ nvT) {
    const int t  = blockIdx.x * 256 + threadIdx.x;   // 0 .. 4096*64-1
    const int n  = t >> 6;
    const int c8 = t & 63;
    const float4 f0 = *(const float4*)(x + (size_t)n * N_IN + c8 * 8);
    const float4 f1 = *(const float4*)(x + (size_t)n * N_IN + c8 * 8 + 4);
    const __half2 a = __floats2half2_rn(f0.x, f0.y);
    const __half2 b = __floats2half2_rn(f0.z, f0.w);
    const __half2 c = __floats2half2_rn(f1.x, f1.y);
    const __half2 d = __floats2half2_rn(f1.z, f1.w);
    uint4 u;
    u.x = *(const uint32_t*)&a; u.y = *(const uint32_t*)&b;
    u.z = *(const uint32_t*)&c; u.w = *(const uint32_t*)&d;
    *(uint4*)(nvT + (size_t)n * NVSTRIDE + c8 * 8) = u;
}

// ---------- fp16 scatter-add (CAS on containing dword; duplicates accumulate) ----------
__device__ __forceinline__ void atomic_add_half(__half* addr, float val) {
    uint32_t* base = (uint32_t*)((size_t)addr & ~(size_t)3);
    const bool hi  = ((size_t)addr & 2) != 0;
    uint32_t old = *base, assumed;
    do {
        assumed = old;
        __half2 h2 = *(__half2*)&assumed;
        float f = (hi ? __high2float(h2) : __low2float(h2)) + val;
        __half2 nh = hi ? __halves2half2(__low2half(h2), __float2half_rn(f))
                        : __halves2half2(__float2half_rn(f), __high2half(h2));
        old = atomicCAS(base, assumed, *(uint32_t*)&nh);
    } while (old != assumed);
}

__global__ __launch_bounds__(256) void k_wfill01(
        const int* __restrict__ s0, const int* __restrict__ d0, const float* __restrict__ w0,
        const int* __restrict__ s1, const int* __restrict__ d1, const float* __restrict__ w1,
        __half* __restrict__ W0d, __half* __restrict__ W1d) {
    const int e = blockIdx.x * 256 + threadIdx.x;
    if (e < E0)  atomic_add_half(W0d + (size_t)d0[e] * K1 + s0[e], w0[e]);
    else { const int i = e - E0; atomic_add_half(W1d + (size_t)d1[i] * K2 + s1[i], w1[i]); }
}

__global__ __launch_bounds__(256) void k_wfill(const int* __restrict__ src,
                                               const int* __restrict__ dst,
                                               const float* __restrict__ w,
                                               __half* __restrict__ Wd, const int K) {
    const int e = blockIdx.x * 256 + threadIdx.x;
    atomic_add_half(Wd + (size_t)dst[e] * K + src[e], w[e]);
}

// ---------- GEMM for levels 1/2: BM=96, BN=128, 256 thr, dbuf + counted vmcnt ----
// Per step: {barrier; STAGE(t+1); vmcnt(7); barrier; compute(t)}. Tile t+1's 7
// loads stay in flight through compute and across the step boundary — vmcnt
// never drains to 0 in the main loop (m218: counted-vs-drain is the +38-73%
// lever). Barrier #1 makes the overwrite of buf[t-1] safe; barrier #2 makes
// all waves' tile-t data visible (vmcnt is per-wave).
__global__ __launch_bounds__(256, 2)
void k_gemm96(const __half* __restrict__ A,    // [M][K] dense W, row stride K
              const __half* __restrict__ Bt,   // nvT, row stride NVSTRIDE
              __half* __restrict__ Ch,         // nvT + col0
              const int K) {
    __shared__ __half lA[2][96 * 64];
    __shared__ __half lB[2][128 * 64];
    const int tid  = threadIdx.x;
    const int lane = tid & 63;
    const int wv   = tid >> 6;
    const int wr   = wv >> 1, wc = wv & 1;
    const int m0   = blockIdx.y * 96;
    const int n0   = blockIdx.x * 128;
    const int lrow = lane >> 3;
    const int lchk = lane & 7;

    f32x4 acc[3][4] = {};

#define STAGE96(BUF, KT) {                                                   \
    _Pragma("unroll")                                                        \
    for (int it = 0; it < 3; ++it) {                                         \
        const int row = it * 32 + wv * 8 + lrow;                             \
        const int sc  = lchk ^ (row & 7);                                    \
        GLL(A + (size_t)(m0 + row) * K + (KT) + sc * 8,                      \
            lA[BUF] + (it * 32 + wv * 8) * 64);                              \
    }                                                                        \
    _Pragma("unroll")                                                        \
    for (int it = 0; it < 4; ++it) {                                         \
        const int row = it * 32 + wv * 8 + lrow;                             \
        const int sc  = lchk ^ (row & 7);                                    \
        GLL(Bt + (size_t)(n0 + row) * NVSTRIDE + (KT) + sc * 8,              \
            lB[BUF] + (it * 32 + wv * 8) * 64);                              \
    }                                                                        \
}

    const int NT = K >> 6;
    STAGE96(0, 0)
    int cur = 0;
    for (int t = 0; t < NT; ++t) {
        __builtin_amdgcn_s_barrier();            // prev compute done: safe to overwrite
        __builtin_amdgcn_sched_barrier(0);
        if (t + 1 < NT) {
            STAGE96(cur ^ 1, (t + 1) << 6)
            asm volatile("s_waitcnt vmcnt(7)" ::: "memory");   // t landed, t+1 flies
        } else {
            asm volatile("s_waitcnt vmcnt(0)" ::: "memory");
        }
        __builtin_amdgcn_sched_barrier(0);
        __builtin_amdgcn_s_barrier();            // all waves' tile-t data in LDS
        __builtin_amdgcn_sched_barrier(0);
#pragma unroll
        for (int kk = 0; kk < 2; ++kk) {
            f16x8 af[3], bf[4];
#pragma unroll
            for (int fm = 0; fm < 3; ++fm) {
                const int row = wr * 48 + fm * 16 + (lane & 15);
                const int ch  = (kk * 4 + (lane >> 4)) ^ (row & 7);
                af[fm] = *(const f16x8*)(lA[cur] + row * 64 + ch * 8);
            }
#pragma unroll
            for (int fn = 0; fn < 4; ++fn) {
                const int row = wc * 64 + fn * 16 + (lane & 15);
                const int ch  = (kk * 4 + (lane >> 4)) ^ (row & 7);
                bf[fn] = *(const f16x8*)(lB[cur] + row * 64 + ch * 8);
            }
#pragma unroll
            for (int fm = 0; fm < 3; ++fm)
#pragma unroll
                for (int fn = 0; fn < 4; ++fn)
                    acc[fm][fn] = __builtin_amdgcn_mfma_f32_16x16x32_f16(
                        af[fm], bf[fn], acc[fm][fn], 0, 0, 0);
        }
        cur ^= 1;
    }
#undef STAGE96

    const int cm = (lane >> 4) << 2;
    const int cn = lane & 15;
#pragma unroll
    for (int fm = 0; fm < 3; ++fm)
#pragma unroll
        for (int fn = 0; fn < 4; ++fn) {
            const f32x4 v = acc[fm][fn];
            const __half2 p0 = __floats2half2_rn(fmaxf(v[0], 0.f), fmaxf(v[1], 0.f));
            const __half2 p1 = __floats2half2_rn(fmaxf(v[2], 0.f), fmaxf(v[3], 0.f));
            const int mm = m0 + wr * 48 + fm * 16 + cm;
            const int nn = n0 + wc * 64 + fn * 16 + cn;
            uint2 u; u.x = *(const uint32_t*)&p0; u.y = *(const uint32_t*)&p1;
            *(uint2*)(Ch + (size_t)nn * NVSTRIDE + mm) = u;
        }
}

// ---------- GEMM for level 3: BM=64, BN=128, 512 thr (8 waves), quad-buffer ----
// depth-2 prefetch, ONE barrier/step: {STAGE(t+2); vmcnt(6); barrier; compute}.
// Overwrite target buf[(t+2)&3] was last read at compute(t-2) — guaranteed done
// by barrier(t-1), so no pre-stage barrier needed. 24 loads/tile, 3 per wave;
// 8 waves = 2/SIMD doubles fill concurrency vs R9's 4-wave version.
__global__ __launch_bounds__(512, 2)
void k_gemm3(const __half* __restrict__ A,     // [512][3584] dense W2
             const __half* __restrict__ Bt,    // nvT
             float* __restrict__ Cf) {         // d_out [4096][512]
    __shared__ __half lA[4][64 * 64];
    __shared__ __half lB[4][128 * 64];
    const int tid  = threadIdx.x;
    const int lane = tid & 63;
    const int wv   = tid >> 6;                  // 0..7
    const int wr   = wv >> 2, wc = wv & 3;      // 2 x 4 wave grid
    const int m0   = blockIdx.y * 64;
    const int n0   = blockIdx.x * 128;
    const int lrow = lane >> 3;
    const int lchk = lane & 7;
    const int K = K3;

    f32x4 acc[2][2] = {};

#define STAGE3(BUF, KT) {                                                    \
    _Pragma("unroll")                                                        \
    for (int i = 0; i < 3; ++i) {                                            \
        const int L = wv * 3 + i;               /* 0..23, wave-uniform */    \
        if (L < 8) {                                                         \
            const int row = L * 8 + lrow;                                    \
            const int sc  = lchk ^ (row & 7);                                \
            GLL(A + (size_t)(m0 + row) * K + (KT) + sc * 8,                  \
                lA[BUF] + L * 512);                                          \
        } else {                                                             \
            const int row = (L - 8) * 8 + lrow;                              \
            const int sc  = lchk ^ (row & 7);                                \
            GLL(Bt + (size_t)(n0 + row) * NVSTRIDE + (KT) + sc * 8,          \
                lB[BUF] + (L - 8) * 512);                                    \
        }                                                                    \
    }                                                                        \
}

    const int NT = K >> 6;   // 56
    STAGE3(0, 0)
    STAGE3(1, 64)
    for (int t = 0; t < NT; ++t) {
        if (t + 2 < NT) {
            STAGE3((t + 2) & 3, (t + 2) << 6)
            asm volatile("s_waitcnt vmcnt(6)" ::: "memory");   // t landed; t+1,t+2 fly
        } else if (t + 1 < NT) {
            asm volatile("s_waitcnt vmcnt(3)" ::: "memory");   // t landed; t+1 flies
        } else {
            asm volatile("s_waitcnt vmcnt(0)" ::: "memory");
        }
        __builtin_amdgcn_sched_barrier(0);
        __builtin_amdgcn_s_barrier();           // all waves' tile-t data in LDS
        __builtin_amdgcn_sched_barrier(0);
        const __half* bA = lA[t & 3];
        const __half* bB = lB[t & 3];
#pragma unroll
        for (int kk = 0; kk < 2; ++kk) {
            f16x8 af[2], bf[2];
#pragma unroll
            for (int fm = 0; fm < 2; ++fm) {
                const int row = wr * 32 + fm * 16 + (lane & 15);
                const int ch  = (kk * 4 + (lane >> 4)) ^ (row & 7);
                af[fm] = *(const f16x8*)(bA + row * 64 + ch * 8);
            }
#pragma unroll
            for (int fn = 0; fn < 2; ++fn) {
                const int row = wc * 32 + fn * 16 + (lane & 15);
                const int ch  = (kk * 4 + (lane >> 4)) ^ (row & 7);
                bf[fn] = *(const f16x8*)(bB + row * 64 + ch * 8);
            }
#pragma unroll
            for (int fm = 0; fm < 2; ++fm)
#pragma unroll
                for (int fn = 0; fn < 2; ++fn)
                    acc[fm][fn] = __builtin_amdgcn_mfma_f32_16x16x32_f16(
                        af[fm], bf[fn], acc[fm][fn], 0, 0, 0);
        }
    }
#undef STAGE3

    const int cm = (lane >> 4) << 2;
    const int cn = lane & 15;
#pragma unroll
    for (int fm = 0; fm < 2; ++fm)
#pragma unroll
        for (int fn = 0; fn < 2; ++fn) {
            const f32x4 v = acc[fm][fn];
            float4 o;
            o.x = fmaxf(v[0], 0.f); o.y = fmaxf(v[1], 0.f);
            o.z = fmaxf(v[2], 0.f); o.w = fmaxf(v[3], 0.f);
            const int mm = m0 + wr * 32 + fm * 16 + cm;
            const int nn = n0 + wc * 32 + fn * 16 + cn;
            *(float4*)(Cf + (size_t)nn * N_OUT + mm) = o;
        }
}

extern "C" void kernel_launch(void* const* d_in, const int* in_sizes, int n_in,
                              void* d_out, int out_size, void* d_ws, size_t ws_size,
                              hipStream_t stream) {
    const float* x  = (const float*)d_in[0];
    const int* s0   = (const int*)d_in[1];
    const int* dd0  = (const int*)d_in[2];
    const float* w0 = (const float*)d_in[3];
    const int* s1   = (const int*)d_in[4];
    const int* dd1  = (const int*)d_in[5];
    const float* w1 = (const float*)d_in[6];
    const int* s2   = (const int*)d_in[7];
    const int* dd2  = (const int*)d_in[8];
    const float* w2 = (const float*)d_in[9];

    char*   ws  = (char*)d_ws;
    __half* nvT = (__half*)ws;
    __half* W0p = (__half*)(ws + NVBYTES);            // region start
    __half* W1p = (__half*)(ws + NVBYTES + W0BYTES);
    __half* W2p = W0p;                                // overlays W0/W1 after GEMM2
    float*  out = (float*)d_out;

    // x -> nvT cols 0..511 (fp32->fp16, coalesced)
    k_xcvt<<<BATCH * 64 / 256, 256, 0, stream>>>(x, nvT);

    // W0 + W1 build, then levels 1/2
    hipMemsetAsync(W0p, 0, W0BYTES + W1BYTES, stream);
    k_wfill01<<<(E0 + E1) / 256, 256, 0, stream>>>(s0, dd0, w0, s1, dd1, w1, W0p, W1p);
    k_gemm96<<<dim3(BATCH / 128, H1 / 96), 256, 0, stream>>>(W0p, nvT, nvT + N_IN, K1);
    k_gemm96<<<dim3(BATCH / 128, H2 / 96), 256, 0, stream>>>(W1p, nvT, nvT + K2, K2);

    // W2 build (overlaying the now-dead W0/W1), then level 3 -> d_out
    hipMemsetAsync(W2p, 0, W2BYTES, stream);
    k_wfill<<<E2 / 256, 256, 0, stream>>>(s2, dd2, w2, W2p, K3);
    k_gemm3<<<dim3(BATCH / 128, N_OUT / 64), 512, 0, stream>>>(W2p, nvT, out);
}